// Round 2
// baseline (5899.227 us; speedup 1.0000x reference)
//
#include <hip/hip_runtime.h>
#include <cstddef>
#include <cstdint>

#define S_LEN   2048
#define D_MODEL 2048
#define NHEAD   16
#define HDIM    128
#define BATCH   4

// ---------------------------------------------------------------------------
// GEMM: C[m][n] = sum_k A[m][k] * W[nOff + n][k]     (W row-major [2048][2048])
// 128x128 tile, 256 threads, 8x8 micro-tile, K-step 16.
// mode 0: RoPE + 1/sqrt(dk) scale, head-split store (Q)
// mode 1: RoPE, head-split store (K)
// mode 2: head-split store (V)
// mode 3: plain store to Out[m][D_MODEL] (accumulate if acc != 0)
// ---------------------------------------------------------------------------
__global__ __launch_bounds__(256) void gemm_kernel(
    const float* __restrict__ A, int lda, int Kdim,
    const float* __restrict__ W,
    float* __restrict__ Out,
    int mode, int nOff, int HG, int acc)
{
    __shared__ float As[16][132];   // [k][m]
    __shared__ float Bs[16][132];   // [k][n]

    const int tid = threadIdx.x;
    const int tx  = tid & 15;        // n micro index
    const int tq  = tid >> 4;        // m micro index
    const int tm  = blockIdx.y * 128;
    const int tn  = blockIdx.x * 128;

    const int r  = tid >> 2;         // 0..63 staging row
    const int kc = (tid & 3) << 2;   // 0,4,8,12

    const float* Ab0 = A + (size_t)(tm + r) * lda + kc;
    const float* Ab1 = A + (size_t)(tm + r + 64) * lda + kc;
    const float* Wb0 = W + (size_t)(nOff + tn + r) * D_MODEL + kc;
    const float* Wb1 = W + (size_t)(nOff + tn + r + 64) * D_MODEL + kc;

    float accv[8][8];
    #pragma unroll
    for (int i = 0; i < 8; ++i)
        #pragma unroll
        for (int j = 0; j < 8; ++j) accv[i][j] = 0.f;

    for (int kk = 0; kk < Kdim; kk += 16) {
        float4 a0 = *(const float4*)(Ab0 + kk);
        float4 a1 = *(const float4*)(Ab1 + kk);
        float4 w0 = *(const float4*)(Wb0 + kk);
        float4 w1 = *(const float4*)(Wb1 + kk);
        __syncthreads();
        As[kc+0][r]    = a0.x; As[kc+1][r]    = a0.y; As[kc+2][r]    = a0.z; As[kc+3][r]    = a0.w;
        As[kc+0][r+64] = a1.x; As[kc+1][r+64] = a1.y; As[kc+2][r+64] = a1.z; As[kc+3][r+64] = a1.w;
        Bs[kc+0][r]    = w0.x; Bs[kc+1][r]    = w0.y; Bs[kc+2][r]    = w0.z; Bs[kc+3][r]    = w0.w;
        Bs[kc+0][r+64] = w1.x; Bs[kc+1][r+64] = w1.y; Bs[kc+2][r+64] = w1.z; Bs[kc+3][r+64] = w1.w;
        __syncthreads();
        #pragma unroll
        for (int k = 0; k < 16; ++k) {
            float4 av0 = *(const float4*)&As[k][tq << 3];
            float4 av1 = *(const float4*)&As[k][(tq << 3) + 4];
            float4 bv0 = *(const float4*)&Bs[k][tx << 3];
            float4 bv1 = *(const float4*)&Bs[k][(tx << 3) + 4];
            float am[8] = {av0.x, av0.y, av0.z, av0.w, av1.x, av1.y, av1.z, av1.w};
            float bn[8] = {bv0.x, bv0.y, bv0.z, bv0.w, bv1.x, bv1.y, bv1.z, bv1.w};
            #pragma unroll
            for (int i = 0; i < 8; ++i)
                #pragma unroll
                for (int j = 0; j < 8; ++j)
                    accv[i][j] = fmaf(am[i], bn[j], accv[i][j]);
        }
    }

    if (mode == 3) {
        #pragma unroll
        for (int i = 0; i < 8; ++i) {
            size_t off = (size_t)(tm + (tq << 3) + i) * D_MODEL + tn + (tx << 3);
            float4 s0 = make_float4(accv[i][0], accv[i][1], accv[i][2], accv[i][3]);
            float4 s1 = make_float4(accv[i][4], accv[i][5], accv[i][6], accv[i][7]);
            if (acc) {
                float4 o0 = *(const float4*)(Out + off);
                float4 o1 = *(const float4*)(Out + off + 4);
                s0.x += o0.x; s0.y += o0.y; s0.z += o0.z; s0.w += o0.w;
                s1.x += o1.x; s1.y += o1.y; s1.z += o1.z; s1.w += o1.w;
            }
            *(float4*)(Out + off)     = s0;
            *(float4*)(Out + off + 4) = s1;
        }
        return;
    }

    // head-split stores (+ optional RoPE). Out layout: [bb][hl][s][d] with
    // bb = local batch within chunk, hl = local head within chunk.
    const int ng = nOff + tn + (tx << 3);   // global feature col, 8 consecutive
    const int hg = ng >> 7;                 // head
    const int d0 = ng & 127;                // within-head dim (multiple of 8)
    const int hl = hg - (nOff >> 7);        // local head within chunk
    const float qscale = 0.08838834764831843f;   // 1/sqrt(128)
    const float negC   = -0.14391156831212786f;  // -ln(10000)/64

    #pragma unroll
    for (int i = 0; i < 8; ++i) {
        const int gm = tm + (tq << 3) + i;
        const int bb = gm >> 11;            // local batch
        const int ss = gm & 2047;
        float v[8];
        #pragma unroll
        for (int j = 0; j < 8; ++j) v[j] = accv[i][j];
        if (mode <= 1) {
            const float fs = (float)ss;
            #pragma unroll
            for (int p = 0; p < 4; ++p) {
                float invf = expf((float)((d0 >> 1) + p) * negC);
                float sn, cs;
                sincosf(fs * invf, &sn, &cs);
                float x1 = v[2*p], x2 = v[2*p+1];
                v[2*p]   = x1 * cs - x2 * sn;
                v[2*p+1] = x1 * sn + x2 * cs;
            }
            if (mode == 0) {
                #pragma unroll
                for (int j = 0; j < 8; ++j) v[j] *= qscale;
            }
        }
        float* dst = Out + ((size_t)(bb * HG + hl) * S_LEN + ss) * HDIM + d0;
        *(float4*)dst       = make_float4(v[0], v[1], v[2], v[3]);
        *(float4*)(dst + 4) = make_float4(v[4], v[5], v[6], v[7]);
    }
}

// ---------------------------------------------------------------------------
// Causal flash attention, fp32 vector ALU.
// Block: 128 q-rows of one (b,h); BK=64; 256 threads.
// LDS: Qs [d][q] 64KB, KPs union (Ks [d][k] -> Ps [q][k]) 32KB, Vs [k][dv] 32KB.
// Q is pre-scaled by 1/sqrt(dk) in the projection epilogue.
// ---------------------------------------------------------------------------
__global__ __launch_bounds__(256) void attn_kernel(
    const float* __restrict__ Q, const float* __restrict__ K,
    const float* __restrict__ V, float* __restrict__ Ctx, int HG)
{
    __shared__ float Qs[128][128];
    __shared__ float KPs[128 * 64];
    __shared__ float Vs[64][128];

    const int qt  = blockIdx.x;        // q tile (128 rows)
    const int bh  = blockIdx.y;        // local (batch, head) pair within chunk
    const int tid = threadIdx.x;
    const int tk  = tid & 15;
    const int tq  = tid >> 4;
    const int q0  = tq << 3;           // 8 q rows per thread
    const int k0  = tk << 2;           // 4 k cols per thread (scores)
    const int dv0 = tk << 3;           // 8 dv cols per thread (PV)

    const size_t base = (size_t)bh * S_LEN * HDIM;
    const float* Qb = Q + base + (size_t)qt * 128 * HDIM;
    const float* Kb = K + base;
    const float* Vb = V + base;

    // stage Q tile transposed: Qs[d][q]
    {
        const int rr = tid >> 2;           // 0..63
        const int cc = (tid & 3) << 2;     // 0,4,8,12
        #pragma unroll
        for (int pass = 0; pass < 16; ++pass) {
            int row = rr + ((pass & 1) << 6);
            int col = cc + ((pass >> 1) << 4);
            float4 t = *(const float4*)(Qb + (size_t)row * HDIM + col);
            Qs[col+0][row] = t.x; Qs[col+1][row] = t.y;
            Qs[col+2][row] = t.z; Qs[col+3][row] = t.w;
        }
    }

    float m_i[8], l_i[8], O[8][8];
    #pragma unroll
    for (int i = 0; i < 8; ++i) {
        m_i[i] = -1e30f; l_i[i] = 0.f;
        #pragma unroll
        for (int j = 0; j < 8; ++j) O[i][j] = 0.f;
    }

    const int kt_end = 2 * qt + 1;
    for (int kt = 0; kt <= kt_end; ++kt) {
        const float* Kt = Kb + (size_t)kt * 64 * HDIM;
        const float* Vt = Vb + (size_t)kt * 64 * HDIM;
        __syncthreads();   // prior PV reads of KPs/Vs complete (also covers Q-stage)
        {
            const int rr = tid >> 2;
            const int cc = (tid & 3) << 2;
            const int dc = tid & 31;
            const int rv = tid >> 5;
            #pragma unroll
            for (int pass = 0; pass < 8; ++pass) {
                int col = cc + (pass << 4);
                float4 t = *(const float4*)(Kt + (size_t)rr * HDIM + col);
                KPs[(col+0)*64 + rr] = t.x;
                KPs[(col+1)*64 + rr] = t.y;
                KPs[(col+2)*64 + rr] = t.z;
                KPs[(col+3)*64 + rr] = t.w;
                int rowv = rv + (pass << 3);
                float4 tv = *(const float4*)(Vt + (size_t)rowv * HDIM + (dc << 2));
                *(float4*)&Vs[rowv][dc << 2] = tv;
            }
        }
        __syncthreads();

        // scores: S[8q][4k]
        float sreg[8][4] = {};
        #pragma unroll 4
        for (int d = 0; d < 128; ++d) {
            float4 a0 = *(const float4*)&Qs[d][q0];
            float4 a1 = *(const float4*)&Qs[d][q0 + 4];
            float4 bv = *(const float4*)&KPs[d * 64 + k0];
            float am0[4] = {a0.x, a0.y, a0.z, a0.w};
            float am1[4] = {a1.x, a1.y, a1.z, a1.w};
            float bn[4]  = {bv.x, bv.y, bv.z, bv.w};
            #pragma unroll
            for (int j = 0; j < 4; ++j)
                #pragma unroll
                for (int i = 0; i < 4; ++i) {
                    sreg[i][j]   = fmaf(am0[i], bn[j], sreg[i][j]);
                    sreg[i+4][j] = fmaf(am1[i], bn[j], sreg[i+4][j]);
                }
        }

        if (kt >= 2 * qt) {   // diagonal blocks: causal mask
            const int qg = qt * 128 + q0;
            const int kg = kt * 64 + k0;
            #pragma unroll
            for (int i = 0; i < 8; ++i)
                #pragma unroll
                for (int j = 0; j < 4; ++j)
                    if (kg + j > qg + i) sreg[i][j] = -1e30f;
        }

        // online softmax update (row stats across 16 tk lanes)
        float fac[8];
        #pragma unroll
        for (int i = 0; i < 8; ++i) {
            float mx = fmaxf(fmaxf(sreg[i][0], sreg[i][1]), fmaxf(sreg[i][2], sreg[i][3]));
            mx = fmaxf(mx, __shfl_xor(mx, 1));
            mx = fmaxf(mx, __shfl_xor(mx, 2));
            mx = fmaxf(mx, __shfl_xor(mx, 4));
            mx = fmaxf(mx, __shfl_xor(mx, 8));
            float mn = fmaxf(m_i[i], mx);
            float f  = __expf(m_i[i] - mn);
            m_i[i] = mn;
            fac[i] = f;
            float rs = 0.f;
            #pragma unroll
            for (int j = 0; j < 4; ++j) {
                sreg[i][j] = __expf(sreg[i][j] - mn);
                rs += sreg[i][j];
            }
            rs += __shfl_xor(rs, 1);
            rs += __shfl_xor(rs, 2);
            rs += __shfl_xor(rs, 4);
            rs += __shfl_xor(rs, 8);
            l_i[i] = l_i[i] * f + rs;
        }

        __syncthreads();   // everyone done reading Ks
        #pragma unroll
        for (int i = 0; i < 8; ++i)
            *(float4*)&KPs[(q0 + i) * 64 + k0] =
                make_float4(sreg[i][0], sreg[i][1], sreg[i][2], sreg[i][3]);
        #pragma unroll
        for (int i = 0; i < 8; ++i)
            #pragma unroll
            for (int j = 0; j < 8; ++j) O[i][j] *= fac[i];
        __syncthreads();   // Ps visible

        // PV: O[8q][8dv] += P[8q][64k] * V[64k][8dv]
        for (int k4 = 0; k4 < 64; k4 += 4) {
            float pam[8][4];
            #pragma unroll
            for (int i = 0; i < 8; ++i) {
                float4 t = *(const float4*)&KPs[(q0 + i) * 64 + k4];
                pam[i][0] = t.x; pam[i][1] = t.y; pam[i][2] = t.z; pam[i][3] = t.w;
            }
            #pragma unroll
            for (int kk = 0; kk < 4; ++kk) {
                const float* vr = &Vs[k4 + kk][dv0];
                float4 b0 = *(const float4*)vr;
                float4 b1 = *(const float4*)(vr + 4);
                #pragma unroll
                for (int i = 0; i < 8; ++i) {
                    float p = pam[i][kk];
                    O[i][0] = fmaf(p, b0.x, O[i][0]);
                    O[i][1] = fmaf(p, b0.y, O[i][1]);
                    O[i][2] = fmaf(p, b0.z, O[i][2]);
                    O[i][3] = fmaf(p, b0.w, O[i][3]);
                    O[i][4] = fmaf(p, b1.x, O[i][4]);
                    O[i][5] = fmaf(p, b1.y, O[i][5]);
                    O[i][6] = fmaf(p, b1.z, O[i][6]);
                    O[i][7] = fmaf(p, b1.w, O[i][7]);
                }
            }
        }
    }

    // epilogue: normalize and store ctx[bb][s][hl*128 + dv]  (chunk-local)
    const int b  = bh / HG;
    const int hl = bh % HG;
    #pragma unroll
    for (int i = 0; i < 8; ++i) {
        float inv = 1.0f / l_i[i];
        int sg = qt * 128 + q0 + i;
        float* dst = Ctx + ((size_t)(b * S_LEN + sg) * (HG * HDIM)) + hl * HDIM + dv0;
        *(float4*)dst       = make_float4(O[i][0]*inv, O[i][1]*inv, O[i][2]*inv, O[i][3]*inv);
        *(float4*)(dst + 4) = make_float4(O[i][4]*inv, O[i][5]*inv, O[i][6]*inv, O[i][7]*inv);
    }
}

extern "C" void kernel_launch(void* const* d_in, const int* in_sizes, int n_in,
                              void* d_out, int out_size, void* d_ws, size_t ws_size,
                              hipStream_t stream) {
    (void)in_sizes; (void)n_in; (void)out_size;
    const float* x  = (const float*)d_in[0];
    const float* wq = (const float*)d_in[1];
    const float* wk = (const float*)d_in[2];
    const float* wv = (const float*)d_in[3];
    const float* wo = (const float*)d_in[4];
    float* out = (float*)d_out;
    float* ws  = (float*)d_ws;

    // STRICT workspace budget. Per (batch,head) pair we need 4 buffers
    // (Q,K,V,ctx) of S*HDIM fp32 = 4 MiB/pair. Choose chunk = BB batches x
    // HG heads, shrinking until it fits ws_size (floor: 1x1 = 4 MiB).
    const size_t perPairBytes = 4ull * S_LEN * HDIM * sizeof(float) * 4; // 4 MiB
    int BB = BATCH, HG = NHEAD;
    while ((size_t)BB * (size_t)HG * perPairBytes > ws_size) {
        if (HG > 1)      HG >>= 1;
        else if (BB > 1) BB >>= 1;
        else break;   // < 4 MiB workspace: nothing smaller exists
    }

    const size_t bufElems = (size_t)BB * HG * S_LEN * HDIM;
    float* Qb = ws;
    float* Kb = ws + bufElems;
    float* Vb = ws + 2 * bufElems;
    float* Cb = ws + 3 * bufElems;

    const int KGc   = HG * HDIM;        // feature cols per chunk
    const int Mrows = BB * S_LEN;       // rows per chunk
    dim3 blk(256);

    for (int b0 = 0; b0 < BATCH; b0 += BB) {
        const float* xb   = x   + (size_t)b0 * S_LEN * D_MODEL;
        float*       outb = out + (size_t)b0 * S_LEN * D_MODEL;
        for (int g = 0; g < NHEAD / HG; ++g) {
            const int nOff = g * KGc;
            dim3 gp(KGc / 128, Mrows / 128);
            gemm_kernel<<<gp, blk, 0, stream>>>(xb, D_MODEL, D_MODEL, wq, Qb, 0, nOff, HG, 0);
            gemm_kernel<<<gp, blk, 0, stream>>>(xb, D_MODEL, D_MODEL, wk, Kb, 1, nOff, HG, 0);
            gemm_kernel<<<gp, blk, 0, stream>>>(xb, D_MODEL, D_MODEL, wv, Vb, 2, nOff, HG, 0);
            attn_kernel<<<dim3(S_LEN / 128, BB * HG), blk, 0, stream>>>(Qb, Kb, Vb, Cb, HG);
            dim3 go(D_MODEL / 128, Mrows / 128);
            gemm_kernel<<<go, blk, 0, stream>>>(Cb, KGc, KGc, wo + nOff, outb, 3, 0, 0, g > 0);
        }
    }
}

// Round 3
// 981.572 us; speedup vs baseline: 6.0100x; 6.0100x over previous
//
#include <hip/hip_runtime.h>
#include <cstddef>
#include <cstdint>
#include <cstring>

#define S_LEN   2048
#define D_MODEL 2048
#define NHEAD   16
#define HDIM    128
#define BATCH   4
#define M_ROWS  (BATCH * S_LEN)   // 8192

typedef unsigned short u16;
typedef short bf16x8 __attribute__((ext_vector_type(8)));
typedef float f32x4 __attribute__((ext_vector_type(4)));

__device__ __forceinline__ float b2f(u16 h) {
    union { uint32_t u; float f; } v; v.u = (uint32_t)h << 16; return v.f;
}
__device__ __forceinline__ u16 f2b(float f) {   // RNE f32->bf16 (inputs finite)
    union { float f; uint32_t u; } v; v.f = f;
    return (u16)((v.u + 0x7FFFu + ((v.u >> 16) & 1u)) >> 16);
}

// async global->LDS, 16B per lane. LDS dest must be wave-uniform base + lane*16
// (linear); swizzles are applied on the GLOBAL source address (m173 pattern).
#define GLOAD16(ldsdst, gsrc) \
    __builtin_amdgcn_global_load_lds((__attribute__((address_space(1))) void*)(gsrc), \
                                     (__attribute__((address_space(3))) void*)(ldsdst), 16, 0, 0)

// ---------------------------------------------------------------------------
// f32 -> bf16 conversion, 8 elems/thread
// ---------------------------------------------------------------------------
__global__ __launch_bounds__(256) void cvt_kernel(const float* __restrict__ in,
                                                  u16* __restrict__ out, int n8) {
    int i = blockIdx.x * 256 + threadIdx.x;
    if (i >= n8) return;
    const float4* pf = (const float4*)in;
    float4 a = pf[2 * i], b = pf[2 * i + 1];
    u16 e[8] = {f2b(a.x), f2b(a.y), f2b(a.z), f2b(a.w),
                f2b(b.x), f2b(b.y), f2b(b.z), f2b(b.w)};
    uint4 v; memcpy(&v, e, 16);
    ((uint4*)out)[i] = v;
}

// ---------------------------------------------------------------------------
// RoPE in-place on bf16 [rows][HDIM]; rows = bh*s, pairs (2p,2p+1) along d.
// scale folds 1/sqrt(dk) into Q.
// ---------------------------------------------------------------------------
__global__ __launch_bounds__(256) void rope_kernel(u16* __restrict__ T, float scale, int nrows) {
    int t = blockIdx.x * 256 + threadIdx.x;       // one per 8 elems
    if (t >= nrows * 16) return;
    const int seg = t & 15;
    const int row = t >> 4;
    const int s = row & (S_LEN - 1);
    const float negC = -0.14391156831212786f;     // -ln(10000)/64
    u16* p = T + (size_t)row * HDIM + seg * 8;
    uint4 v = *(const uint4*)p;
    u16 e[8]; memcpy(e, &v, 16);
    #pragma unroll
    for (int j = 0; j < 4; ++j) {
        float x1 = b2f(e[2 * j]), x2 = b2f(e[2 * j + 1]);
        float ang = (float)s * __expf((float)(seg * 4 + j) * negC);
        float sn, cs;
        sincosf(ang, &sn, &cs);
        e[2 * j]     = f2b((x1 * cs - x2 * sn) * scale);
        e[2 * j + 1] = f2b((x1 * sn + x2 * cs) * scale);
    }
    memcpy(&v, e, 16);
    *(uint4*)p = v;
}

// ---------------------------------------------------------------------------
// bf16 MFMA GEMM: C[m][n] = sum_k A[m][k] * B[n][k]   (both row-major, bf16)
// 128x128 tile, BK=64, 256 thr = 4 waves (2x2 of 64x64), 16x16x32 MFMA.
// LDS [128 rows][8 chunks of 16B], chunk XOR-swizzled by (row&7) via
// pre-swizzled global source; ds_read_b128 fragments are 2-way (free).
// mode 0: bf16 head-split store [b][h][s][d]   (Q/K before RoPE)
// mode 1: bf16 Vt store [b][h][d][s]           (call with A=wv, B=x)
// mode 2: f32 store out[m][D_MODEL] (+= if acc)
// ---------------------------------------------------------------------------
__global__ __launch_bounds__(256) void gemm_bf16(
    const u16* __restrict__ A, int lda,
    const u16* __restrict__ B, int ldb,
    int Kdim, int mode, int HG, int acc,
    u16* __restrict__ outH, float* __restrict__ outF)
{
    __shared__ u16 As[128 * 64];
    __shared__ u16 Bs[128 * 64];

    const int tid = threadIdx.x;
    const int l = tid & 63, wid = tid >> 6;
    const int wr = wid >> 1, wc = wid & 1;
    const int lr = l & 15, lk = l >> 4;
    const int tm = blockIdx.y * 128, tn = blockIdx.x * 128;
    const int srow = tid >> 3;     // 0..31 staging row within pass
    const int sch  = tid & 7;      // chunk 0..7

    f32x4 acc4[4][4];
    #pragma unroll
    for (int i = 0; i < 4; ++i)
        #pragma unroll
        for (int j = 0; j < 4; ++j)
            acc4[i][j] = (f32x4){0.f, 0.f, 0.f, 0.f};

    for (int kk = 0; kk < Kdim; kk += 64) {
        __syncthreads();
        #pragma unroll
        for (int p = 0; p < 4; ++p) {
            const int row = p * 32 + srow;
            const int gc = kk + ((sch ^ (row & 7)) << 3);
            GLOAD16(&As[(size_t)(p * 256 + tid) * 8], A + (size_t)(tm + row) * lda + gc);
            GLOAD16(&Bs[(size_t)(p * 256 + tid) * 8], B + (size_t)(tn + row) * ldb + gc);
        }
        __syncthreads();   // compiler drains vmcnt before this barrier
        #pragma unroll
        for (int kh = 0; kh < 2; ++kh) {
            bf16x8 af[4], bfr[4];
            #pragma unroll
            for (int mi = 0; mi < 4; ++mi) {
                const int row = wr * 64 + mi * 16 + lr;
                af[mi] = *(const bf16x8*)&As[row * 64 + (((kh * 4 + lk) ^ (row & 7)) << 3)];
            }
            #pragma unroll
            for (int nj = 0; nj < 4; ++nj) {
                const int row = wc * 64 + nj * 16 + lr;
                bfr[nj] = *(const bf16x8*)&Bs[row * 64 + (((kh * 4 + lk) ^ (row & 7)) << 3)];
            }
            #pragma unroll
            for (int mi = 0; mi < 4; ++mi)
                #pragma unroll
                for (int nj = 0; nj < 4; ++nj)
                    acc4[mi][nj] = __builtin_amdgcn_mfma_f32_16x16x32_bf16(
                        af[mi], bfr[nj], acc4[mi][nj], 0, 0, 0);
        }
    }

    // epilogue: C/D layout col = lane&15, row = (lane>>4)*4 + reg  [m89-verified]
    #pragma unroll
    for (int mi = 0; mi < 4; ++mi) {
        #pragma unroll
        for (int nj = 0; nj < 4; ++nj) {
            #pragma unroll
            for (int r = 0; r < 4; ++r) {
                const int gm = tm + wr * 64 + mi * 16 + lk * 4 + r;
                const int gn = tn + wc * 64 + nj * 16 + lr;
                const float val = acc4[mi][nj][r];
                if (mode == 2) {
                    size_t off = (size_t)gm * D_MODEL + gn;
                    outF[off] = acc ? (outF[off] + val) : val;
                } else if (mode == 0) {
                    const int b = gm >> 11, s = gm & 2047;
                    const int h = gn >> 7,  d = gn & 127;
                    outH[(((size_t)b * HG + h) * S_LEN + s) * HDIM + d] = f2b(val);
                } else {   // mode 1: Vt[b][h][d][s]; gm = feature (local), gn = sample
                    const int h = gm >> 7,  d = gm & 127;
                    const int b = gn >> 11, s = gn & 2047;
                    outH[(((size_t)b * HG + h) * HDIM + d) * S_LEN + s] = f2b(val);
                }
            }
        }
    }
}

// ---------------------------------------------------------------------------
// Causal flash attention, bf16 MFMA.
// Block: 128 q-rows of one (b,h), 4 waves x 32q, K/V tiles of 64.
// LDS: Qs 32K [128][256B], Ks 16K [64][256B], Vs 16K [128d][128B], Ps 16K
// [128q][128B]; all chunk-XOR-swizzled. 80 KB -> 2 blocks/CU.
// Q pre-scaled by 1/sqrt(dk); P routed via LDS (wave-private rows).
// ---------------------------------------------------------------------------
__global__ __launch_bounds__(256) void attn_mfma(
    const u16* __restrict__ Q, const u16* __restrict__ K,
    const u16* __restrict__ Vt, u16* __restrict__ Ctx, int HG)
{
    __shared__ u16 Qs[128 * 128];
    __shared__ u16 Ks[64 * 128];
    __shared__ u16 Vs[128 * 64];
    __shared__ u16 Ps[128 * 64];

    const int qt = blockIdx.x, bh = blockIdx.y;
    const int tid = threadIdx.x;
    const int l = tid & 63, wid = tid >> 6;
    const int lr = l & 15, lk = l >> 4;
    const size_t base = (size_t)bh * S_LEN * HDIM;

    // stage Q tile (swizzled source, linear LDS)
    #pragma unroll
    for (int p = 0; p < 8; ++p) {
        const int row = p * 16 + (tid >> 4), ch = tid & 15;
        GLOAD16(&Qs[(size_t)(p * 256 + tid) * 8],
                Q + base + (size_t)(qt * 128 + row) * HDIM + ((ch ^ (row & 7)) << 3));
    }

    f32x4 O[2][8];
    float m_i[2][4], l_i[2][4];
    #pragma unroll
    for (int mi = 0; mi < 2; ++mi) {
        #pragma unroll
        for (int dj = 0; dj < 8; ++dj) O[mi][dj] = (f32x4){0.f, 0.f, 0.f, 0.f};
        #pragma unroll
        for (int r = 0; r < 4; ++r) { m_i[mi][r] = -1e30f; l_i[mi][r] = 0.f; }
    }

    const int ktEnd = 2 * qt + 1;
    for (int kt = 0; kt <= ktEnd; ++kt) {
        __syncthreads();   // all waves done with previous Ks/Vs
        #pragma unroll
        for (int p = 0; p < 4; ++p) {
            const int row = p * 16 + (tid >> 4), ch = tid & 15;
            GLOAD16(&Ks[(size_t)(p * 256 + tid) * 8],
                    K + base + (size_t)(kt * 64 + row) * HDIM + ((ch ^ (row & 7)) << 3));
            const int rv = p * 32 + (tid >> 3), cv = tid & 7;
            GLOAD16(&Vs[(size_t)(p * 256 + tid) * 8],
                    Vt + base + (size_t)rv * S_LEN + kt * 64 + ((cv ^ (rv & 7)) << 3));
        }
        __syncthreads();   // staging complete (vmcnt drained by compiler)

        // ---- S = Q.K^T  (32q x 64k per wave) ----
        f32x4 Sv[2][4];
        #pragma unroll
        for (int mi = 0; mi < 2; ++mi)
            #pragma unroll
            for (int nj = 0; nj < 4; ++nj) Sv[mi][nj] = (f32x4){0.f, 0.f, 0.f, 0.f};
        #pragma unroll
        for (int kh = 0; kh < 4; ++kh) {
            bf16x8 qa[2], kb[4];
            #pragma unroll
            for (int mi = 0; mi < 2; ++mi) {
                const int row = wid * 32 + mi * 16 + lr;
                qa[mi] = *(const bf16x8*)&Qs[row * 128 + (((kh * 4 + lk) ^ (row & 7)) << 3)];
            }
            #pragma unroll
            for (int nj = 0; nj < 4; ++nj) {
                const int kr = nj * 16 + lr;
                kb[nj] = *(const bf16x8*)&Ks[kr * 128 + (((kh * 4 + lk) ^ (kr & 7)) << 3)];
            }
            #pragma unroll
            for (int mi = 0; mi < 2; ++mi)
                #pragma unroll
                for (int nj = 0; nj < 4; ++nj)
                    Sv[mi][nj] = __builtin_amdgcn_mfma_f32_16x16x32_bf16(
                        qa[mi], kb[nj], Sv[mi][nj], 0, 0, 0);
        }

        // causal mask (diagonal tiles only)
        if (kt >= 2 * qt) {
            #pragma unroll
            for (int mi = 0; mi < 2; ++mi)
                #pragma unroll
                for (int nj = 0; nj < 4; ++nj)
                    #pragma unroll
                    for (int r = 0; r < 4; ++r) {
                        const int qg = qt * 128 + wid * 32 + mi * 16 + lk * 4 + r;
                        const int kg = kt * 64 + nj * 16 + lr;
                        if (kg > qg) Sv[mi][nj][r] = -1e30f;
                    }
        }

        // ---- online softmax (rows live across the 16 lanes sharing lk) ----
        float fac[2][4];
        #pragma unroll
        for (int mi = 0; mi < 2; ++mi) {
            #pragma unroll
            for (int r = 0; r < 4; ++r) {
                float mx = fmaxf(fmaxf(Sv[mi][0][r], Sv[mi][1][r]),
                                 fmaxf(Sv[mi][2][r], Sv[mi][3][r]));
                mx = fmaxf(mx, __shfl_xor(mx, 1));
                mx = fmaxf(mx, __shfl_xor(mx, 2));
                mx = fmaxf(mx, __shfl_xor(mx, 4));
                mx = fmaxf(mx, __shfl_xor(mx, 8));
                const float mn = fmaxf(m_i[mi][r], mx);
                const float f = __expf(m_i[mi][r] - mn);
                m_i[mi][r] = mn; fac[mi][r] = f;
                float rs = 0.f;
                #pragma unroll
                for (int nj = 0; nj < 4; ++nj) {
                    const float pv = __expf(Sv[mi][nj][r] - mn);
                    Sv[mi][nj][r] = pv; rs += pv;
                }
                rs += __shfl_xor(rs, 1);
                rs += __shfl_xor(rs, 2);
                rs += __shfl_xor(rs, 4);
                rs += __shfl_xor(rs, 8);
                l_i[mi][r] = l_i[mi][r] * f + rs;
            }
        }
        #pragma unroll
        for (int mi = 0; mi < 2; ++mi)
            #pragma unroll
            for (int dj = 0; dj < 8; ++dj)
                #pragma unroll
                for (int r = 0; r < 4; ++r) O[mi][dj][r] *= fac[mi][r];

        // ---- P -> LDS bf16 (wave-private rows; no barrier needed) ----
        #pragma unroll
        for (int mi = 0; mi < 2; ++mi)
            #pragma unroll
            for (int nj = 0; nj < 4; ++nj)
                #pragma unroll
                for (int r = 0; r < 4; ++r) {
                    const int row = wid * 32 + mi * 16 + lk * 4 + r;
                    const int col = nj * 16 + lr;
                    Ps[row * 64 + (((col >> 3) ^ (row & 7)) << 3) + (col & 7)] =
                        f2b(Sv[mi][nj][r]);
                }

        // ---- O += P.V ----
        #pragma unroll
        for (int kh = 0; kh < 2; ++kh) {
            bf16x8 pa[2], vb[8];
            #pragma unroll
            for (int mi = 0; mi < 2; ++mi) {
                const int row = wid * 32 + mi * 16 + lr;
                pa[mi] = *(const bf16x8*)&Ps[row * 64 + (((kh * 4 + lk) ^ (row & 7)) << 3)];
            }
            #pragma unroll
            for (int dj = 0; dj < 8; ++dj) {
                const int dr = dj * 16 + lr;
                vb[dj] = *(const bf16x8*)&Vs[dr * 64 + (((kh * 4 + lk) ^ (dr & 7)) << 3)];
            }
            #pragma unroll
            for (int mi = 0; mi < 2; ++mi)
                #pragma unroll
                for (int dj = 0; dj < 8; ++dj)
                    O[mi][dj] = __builtin_amdgcn_mfma_f32_16x16x32_bf16(
                        pa[mi], vb[dj], O[mi][dj], 0, 0, 0);
        }
    }

    // epilogue: ctx[b][s][h*128 + d] bf16
    const int b = bh / HG, h = bh % HG;
    const int ncols = HG * HDIM;
    #pragma unroll
    for (int mi = 0; mi < 2; ++mi)
        #pragma unroll
        for (int dj = 0; dj < 8; ++dj)
            #pragma unroll
            for (int r = 0; r < 4; ++r) {
                const int s = qt * 128 + wid * 32 + mi * 16 + lk * 4 + r;
                const int d = dj * 16 + lr;
                Ctx[((size_t)b * S_LEN + s) * ncols + h * HDIM + d] =
                    f2b(O[mi][dj][r] / l_i[mi][r]);
            }
}

extern "C" void kernel_launch(void* const* d_in, const int* in_sizes, int n_in,
                              void* d_out, int out_size, void* d_ws, size_t ws_size,
                              hipStream_t stream) {
    (void)in_sizes; (void)n_in; (void)out_size;
    const float* x  = (const float*)d_in[0];
    const float* wq = (const float*)d_in[1];
    const float* wk = (const float*)d_in[2];
    const float* wv = (const float*)d_in[3];
    const float* wo = (const float*)d_in[4];
    float* out = (float*)d_out;
    u16* ws16 = (u16*)d_ws;

    const size_t xN = (size_t)M_ROWS * D_MODEL;      // 16.7M
    const size_t wN = (size_t)D_MODEL * D_MODEL;     // 4.2M
    u16* xb  = ws16;
    u16* wqb = xb + xN;
    u16* wkb = wqb + wN;
    u16* wvb = wkb + wN;
    u16* wob = wvb + wN;
    u16* bufs = wob + wN;
    const size_t convBytes = (xN + 4 * wN) * 2;      // 67 MB

    // head-group chunking only if ws is too small (measured ws >= 256 MiB -> G=1)
    int G = 1;
    while (G < 16 &&
           convBytes + 4ull * ((size_t)BATCH * (NHEAD / G) * S_LEN * HDIM * 2) > ws_size)
        G <<= 1;
    const int HG = NHEAD / G;
    const size_t bufE = (size_t)BATCH * HG * S_LEN * HDIM;
    u16* Qb  = bufs;
    u16* Kb  = bufs + bufE;
    u16* Vtb = bufs + 2 * bufE;
    u16* Cb  = bufs + 3 * bufE;

    dim3 blk(256);
    // convert inputs to bf16
    cvt_kernel<<<(int)((xN / 8 + 255) / 256), blk, 0, stream>>>(x, xb, (int)(xN / 8));
    cvt_kernel<<<(int)((wN / 8 + 255) / 256), blk, 0, stream>>>(wq, wqb, (int)(wN / 8));
    cvt_kernel<<<(int)((wN / 8 + 255) / 256), blk, 0, stream>>>(wk, wkb, (int)(wN / 8));
    cvt_kernel<<<(int)((wN / 8 + 255) / 256), blk, 0, stream>>>(wv, wvb, (int)(wN / 8));
    cvt_kernel<<<(int)((wN / 8 + 255) / 256), blk, 0, stream>>>(wo, wob, (int)(wN / 8));

    const float qscale = 0.08838834764831843f;   // 1/sqrt(128)
    for (int g = 0; g < G; ++g) {
        const int nOff = g * HG * HDIM;
        // Q/K projections: [8192] x [HG*128], head-split store
        gemm_bf16<<<dim3(HG, 64), blk, 0, stream>>>(
            xb, D_MODEL, wqb + (size_t)nOff * D_MODEL, D_MODEL, D_MODEL, 0, HG, 0, Qb, nullptr);
        gemm_bf16<<<dim3(HG, 64), blk, 0, stream>>>(
            xb, D_MODEL, wkb + (size_t)nOff * D_MODEL, D_MODEL, D_MODEL, 0, HG, 0, Kb, nullptr);
        // V projection, operand-swapped -> Vt[b][h][d][s]
        gemm_bf16<<<dim3(64, HG), blk, 0, stream>>>(
            wvb + (size_t)nOff * D_MODEL, D_MODEL, xb, D_MODEL, D_MODEL, 1, HG, 0, Vtb, nullptr);
        // RoPE (Q also scaled by 1/sqrt(dk))
        const int nrows = BATCH * HG * S_LEN;
        rope_kernel<<<nrows / 16, blk, 0, stream>>>(Qb, qscale, nrows);
        rope_kernel<<<nrows / 16, blk, 0, stream>>>(Kb, 1.0f, nrows);
        // attention
        attn_mfma<<<dim3(S_LEN / 128, BATCH * HG), blk, 0, stream>>>(Qb, Kb, Vtb, Cb, HG);
        // output projection (f32, accumulate across groups)
        gemm_bf16<<<dim3(D_MODEL / 128, M_ROWS / 128), blk, 0, stream>>>(
            Cb, HG * HDIM, wob + nOff, D_MODEL, HG * HDIM, 2, HG, g > 0, nullptr, out);
    }
}